// Round 3
// baseline (942.417 us; speedup 1.0000x reference)
//
#include <hip/hip_runtime.h>
#include <hip/hip_bf16.h>

// Linear: C[M,N] = A[M,K] @ W[N,K]^T + bias[N]. fp32 in/out (harness maps fp16
// reference -> fp32 buffers), bf16 MFMA compute (2% threshold).
//
// Round 10: FUSE the fp32->bf16 pack into the GEMM. Pack was ~285 us at
// ~1.1 TB/s, invariant across three structural rewrites (r0/r1/r2) and never
// diagnosable (below top-5 cutoff every round). Instead of a 4th guess:
// delete the phase. The fused GEMM keeps the verified MFMA/read/epilogue side
// BYTE-IDENTICAL (same swizzled physical LDS layout, bank-conflict 0); only
// staging changes: global_load_dwordx4 fp32 -> v_perm bf16-pack ->
// swizzled ds_write_b128, with a 1-deep rotation (tile kt+1's loads issue
// before kt's MFMA barrier, hiding HBM latency under the MFMA phase).
//   * plain cached loads (NOT nontemporal): inputs are now reused across
//     blocks (A panel x32, W panel x64) and must stay L3/L2-resident.
//   * XCD-bijective block swizzle (2048 blocks, %8==0): each XCD's 256
//     blocks span 8 bm-rows -> per-kt L2 working set ~1.1 MiB < 4 MiB.
//   * __launch_bounds__(256,3): acc 64 + staged fp32 64 + frags 32 VGPR
//     ~ 170 cap. Watch VGPR_Count next round for spill evidence.
// No workspace needed -> single kernel, two fewer launches.

typedef unsigned short u16;
typedef unsigned int u32;
typedef __bf16 bf16x8 __attribute__((ext_vector_type(8)));
typedef float f32x4 __attribute__((ext_vector_type(4)));
typedef u32 u32x4 __attribute__((ext_vector_type(4)));

#define M_DIM 8192
#define N_DIM 4096
#define K_DIM 4096
#define BM 128
#define BN 128
#define BK 64
#define KT (K_DIM / BK)                 // 64 k-tiles
#define TILE_ELEMS (BM * BK)            // 8192 bf16 per tile

// pack two fp32 -> (bf16(hi)<<16)|bf16(lo) by byte-perm truncation
__device__ __forceinline__ u32 pack2bf(float lo, float hi) {
    return __builtin_amdgcn_perm(__float_as_uint(hi), __float_as_uint(lo),
                                 0x07060302u);
}

// ---------------- Fused convert + swizzled-stage + GEMM ----------------
// LDS physical layout (identical to the verified packed kernel): tile-major
// [row][chunk]; physical 16B chunk cp at row r holds source chunk cp^(r&7).
// Staging map: srow=tid>>3 (0..31, +it*32), sc=tid&7; since (srow+it*32)&7
// == srow&7, each thread's physical chunk cpA = sc^(srow&7) is constant.
// Read side: logical k-chunk kc=quad+ks8 at row aRow+mi*16 lives at physical
// cp = kc ^ (l16&7) — byte-identical to the verified gemm_packed_kernel.
__global__ __launch_bounds__(256, 3) void linear_fused_kernel(
    const float* __restrict__ A,     // [8192, 4096] fp32
    const float* __restrict__ W,     // [4096, 4096] fp32
    const float* __restrict__ bias,  // [4096] fp32
    float* __restrict__ C)           // [8192, 4096] fp32
{
    __shared__ __attribute__((aligned(16))) __bf16 sA[TILE_ELEMS];
    __shared__ __attribute__((aligned(16))) __bf16 sB[TILE_ELEMS];

    const int tid  = threadIdx.x;
    const int lane = tid & 63;
    const int wave = tid >> 6;
    const int quad = lane >> 4;
    const int l16  = lane & 15;
    const int wm   = wave >> 1;       // 2x2 wave grid, wave tile 64x64
    const int wn   = wave & 1;

    // XCD-bijective swizzle: 2048 blocks round-robin XCDs by bid%8; give each
    // XCD a contiguous tile range (8 bm-rows x 32 bn) for L2 panel sharing.
    const int bid = blockIdx.x;
    const int swz = (bid & 7) * 256 + (bid >> 3);
    const int bm  = swz >> 5;         // 0..63
    const int bn  = swz & 31;         // 0..31

    // staging map
    const int srow = tid >> 3;        // 0..31 (+ it*32)
    const int sc   = tid & 7;         // source chunk (8 floats)
    const int cpA  = sc ^ (srow & 7); // physical chunk (constant per thread)
    const int sOff = srow * BK + cpA * 8;   // element offset in LDS tile

    const float* aBase = A + (size_t)(bm * BM + srow) * K_DIM + sc * 8;
    const float* wBase = W + (size_t)(bn * BN + srow) * K_DIM + sc * 8;

    f32x4 acc[4][4];
#pragma unroll
    for (int i = 0; i < 4; ++i)
#pragma unroll
        for (int j = 0; j < 4; ++j)
            acc[i][j] = f32x4{0.f, 0.f, 0.f, 0.f};

    const int aRow = wm * 64 + l16;   // + mi*16
    const int bRow = wn * 64 + l16;   // + ni*16
    const int cswz = l16 & 7;

    f32x4 ga[4][2], gb[4][2];         // in-flight fp32 stage (64 VGPR)
#pragma unroll
    for (int it = 0; it < 4; ++it) {  // prologue: tile 0 loads
        const float* pa = aBase + (size_t)(it * 32) * K_DIM;
        const float* pb = wBase + (size_t)(it * 32) * K_DIM;
        ga[it][0] = *(const f32x4*)pa;
        ga[it][1] = *(const f32x4*)(pa + 4);
        gb[it][0] = *(const f32x4*)pb;
        gb[it][1] = *(const f32x4*)(pb + 4);
    }

    for (int kt = 0; kt < KT; ++kt) {
        __syncthreads();              // previous tile's MFMA done reading LDS

        // convert + swizzled store of tile kt
#pragma unroll
        for (int it = 0; it < 4; ++it) {
            *(u32x4*)&sA[sOff + it * 2048] =
                u32x4{pack2bf(ga[it][0][0], ga[it][0][1]),
                      pack2bf(ga[it][0][2], ga[it][0][3]),
                      pack2bf(ga[it][1][0], ga[it][1][1]),
                      pack2bf(ga[it][1][2], ga[it][1][3])};
            *(u32x4*)&sB[sOff + it * 2048] =
                u32x4{pack2bf(gb[it][0][0], gb[it][0][1]),
                      pack2bf(gb[it][0][2], gb[it][0][3]),
                      pack2bf(gb[it][1][0], gb[it][1][1]),
                      pack2bf(gb[it][1][2], gb[it][1][3])};
        }

        // issue tile kt+1 loads now; they complete during this tile's MFMAs
        const int ktn = (kt + 1) & (KT - 1);   // wrap: harmless reload of t0
#pragma unroll
        for (int it = 0; it < 4; ++it) {
            const float* pa = aBase + (size_t)(it * 32) * K_DIM + ktn * BK;
            const float* pb = wBase + (size_t)(it * 32) * K_DIM + ktn * BK;
            ga[it][0] = *(const f32x4*)pa;
            ga[it][1] = *(const f32x4*)(pa + 4);
            gb[it][0] = *(const f32x4*)pb;
            gb[it][1] = *(const f32x4*)(pb + 4);
        }

        __syncthreads();              // tile kt staged

#pragma unroll
        for (int ks8 = 0; ks8 < 8; ks8 += 4) {   // k-chunk = quad + {0,4}
            const int cp = (quad + ks8) ^ cswz;   // physical chunk
            bf16x8 af[4], bfr[4];
#pragma unroll
            for (int mi = 0; mi < 4; ++mi)
                af[mi] = *(const bf16x8*)&sA[(aRow + mi * 16) * BK + cp * 8];
#pragma unroll
            for (int ni = 0; ni < 4; ++ni)
                bfr[ni] = *(const bf16x8*)&sB[(bRow + ni * 16) * BK + cp * 8];
#pragma unroll
            for (int mi = 0; mi < 4; ++mi)
#pragma unroll
                for (int ni = 0; ni < 4; ++ni)
                    acc[mi][ni] = __builtin_amdgcn_mfma_f32_16x16x32_bf16(
                        af[mi], bfr[ni], acc[mi][ni], 0, 0, 0);
        }
    }

    // epilogue: C/D layout col = lane&15, row = quad*4 + reg; fp32 out + bias
    const int colBase = bn * BN + wn * 64 + l16;
    const int rowBase = bm * BM + wm * 64 + quad * 4;
#pragma unroll
    for (int ni = 0; ni < 4; ++ni) {
        const int col = colBase + ni * 16;
        const float bv = bias[col];
#pragma unroll
        for (int mi = 0; mi < 4; ++mi) {
            const int row = rowBase + mi * 16;
#pragma unroll
            for (int r = 0; r < 4; ++r)
                C[(size_t)(row + r) * N_DIM + col] = acc[mi][ni][r] + bv;
        }
    }
}

extern "C" void kernel_launch(void* const* d_in, const int* in_sizes, int n_in,
                              void* d_out, int out_size, void* d_ws, size_t ws_size,
                              hipStream_t stream) {
    const float* x = (const float*)d_in[0];   // [8192, 4096]
    const float* w = (const float*)d_in[1];   // [4096, 4096]
    const float* b = (const float*)d_in[2];   // [4096]
    float* out = (float*)d_out;
    (void)d_ws; (void)ws_size;

    linear_fused_kernel<<<dim3(2048), 256, 0, stream>>>(x, w, b, out);
}

// Round 4
// 487.883 us; speedup vs baseline: 1.9316x; 1.9316x over previous
//
#include <hip/hip_runtime.h>
#include <hip/hip_bf16.h>

// Linear: C[M,N] = A[M,K] @ W[N,K]^T + bias[N]. fp32 in/out (harness maps fp16
// reference -> fp32 buffers), bf16 MFMA compute (2% threshold).
//
// Round 11: r3's single-kernel run exposed a ~172 us HARNESS overhead inside
// dur_us (942 bench vs 770 kernel, nothing else dispatched). Re-attribution:
// pack was always ~70 us (near its 48 us roofline), gemm 242 us is the lever.
//   * pack: reverted to the exact r0 version (best measured shape).
//   * gemm: 256x256 / BK=64 / 512 thr / 8 waves (2Mx4N) / double-buffered
//     128 KiB LDS / 4-phase-per-K-tile schedule (guide T3+T4+T5):
//     per phase {ds_read quadrant (+B once) | issue prefetch g2l (ph0-1) |
//     s_barrier | setprio(1) 16xMFMA setprio(0) | s_barrier}; ONE
//     vmcnt(0)+barrier per K-tile at buffer swap, with ~3 phases of MFMA
//     cover between prefetch issue and the wait (old kernel had ZERO cover:
//     issue -> drain -> barrier every tile). Packed tiles are contiguous,
//     pre-XOR-swizzled 16 KB blocks -> linear global_load_lds, 0 bank
//     conflicts on ds_read_b128 (measured in the 128^2 ancestor).
// Predicted: gemm 170-200 us (MfmaUtil 56-66%), total ~420-440.

typedef unsigned short u16;
typedef unsigned int u32;
typedef __bf16 bf16x8 __attribute__((ext_vector_type(8)));
typedef float f32x4 __attribute__((ext_vector_type(4)));
typedef u32 u32x4 __attribute__((ext_vector_type(4)));

#define M_DIM 8192
#define N_DIM 4096
#define K_DIM 4096
#define BM 128            // pack panel height (unchanged)
#define BK 64
#define KT (K_DIM / BK)                 // 64 k-tiles
#define TILE_ELEMS (BM * BK)            // 8192 bf16 per packed tile (16 KB)
#define A_CHUNKS ((M_DIM / BM) * KT * (TILE_ELEMS / 8))   // 4,194,304
#define W_CHUNKS ((N_DIM / BN128) * KT * (TILE_ELEMS / 8))
#define BN128 128
#define A_PACK_BYTES ((size_t)A_CHUNKS * 16)              // 64 MiB
#define W_PACK_BYTES ((size_t)(N_DIM / BN128) * KT * (TILE_ELEMS / 8) * 16) // 32 MiB
#define W_CHUNKS_N ((N_DIM / BN128) * KT * (TILE_ELEMS / 8))  // 2,097,152

// pack two fp32 -> (bf16(hi)<<16)|bf16(lo) by byte-perm truncation
__device__ __forceinline__ u32 pack2bf(float lo, float hi) {
    return __builtin_amdgcn_perm(__float_as_uint(hi), __float_as_uint(lo),
                                 0x07060302u);
}

__device__ __forceinline__ void g2l16(const u16* g, __bf16* l) {
    __builtin_amdgcn_global_load_lds((__attribute__((address_space(1))) void*)g,
                                     (__attribute__((address_space(3))) void*)l,
                                     16, 0, 0);
}

// ---------------- Phase 1: convert + tile-pack + swizzle (r0 version) -------
// One thread per 16B packed chunk; source chunk = phys ^ (row&7) (within the
// row's 128B line -> wave reads whole lines, permuted; writes fully linear).
__global__ __launch_bounds__(256) void pack_bf16_kernel(
    const float* __restrict__ A, const float* __restrict__ W,
    u32x4* __restrict__ aP, u32x4* __restrict__ wP)
{
    int gid = blockIdx.x * 256 + threadIdx.x;
    const float* src;
    u32x4* dst;
    int id;
    if (gid < A_CHUNKS) { src = A; dst = aP; id = gid; }
    else                { src = W; dst = wP; id = gid - A_CHUNKS; }

    const int tile = id >> 10;         // 1024 chunks per tile
    const int slot = id & 1023;
    const int row  = slot >> 3;        // 0..127
    const int cp   = slot & 7;         // physical chunk in packed layout
    const int rb   = tile >> 6;        // row-block (mt or nt)
    const int kt   = tile & (KT - 1);
    const int sc   = cp ^ (row & 7);   // source (logical) chunk

    const float* p = src + (size_t)(rb * BM + row) * K_DIM + kt * BK + sc * 8;
    f32x4 v0 = __builtin_nontemporal_load((const f32x4*)(p));
    f32x4 v1 = __builtin_nontemporal_load((const f32x4*)(p + 4));
    dst[id] = u32x4{pack2bf(v0[0], v0[1]), pack2bf(v0[2], v0[3]),
                    pack2bf(v1[0], v1[1]), pack2bf(v1[2], v1[3])};
}

// ---------------- Phase 2: 256x256 4-phase double-buffered GEMM -------------
// Consumes packed 128x64 tiles in PAIRS: block (bm2,bn2) uses A panels
// {2bm2, 2bm2+1} and W panels {2bn2, 2bn2+1}. LDS sub-tile s holds panel
// p0+s linearly (identical byte layout to the verified 128^2 kernel, so the
// ds_read/MFMA side is byte-identical per sub-tile; bank-conflict 0).
__global__ __launch_bounds__(512, 2) void gemm256_8ph_kernel(
    const u16* __restrict__ aP,      // packed A tiles (128x64, swizzled)
    const u16* __restrict__ wP,      // packed W tiles (128x64, swizzled)
    const float* __restrict__ bias,  // [N] fp32
    float* __restrict__ C)           // [M, N] fp32
{
    __shared__ __attribute__((aligned(16))) __bf16 sA[2][2 * TILE_ELEMS];
    __shared__ __attribute__((aligned(16))) __bf16 sB[2][2 * TILE_ELEMS];

    const int tid  = threadIdx.x;
    const int lane = tid & 63;
    const int wid  = tid >> 6;        // 0..7
    const int quad = lane >> 4;
    const int l16  = lane & 15;
    const int wm2  = wid >> 2;        // 0..1  (M half)
    const int wn2  = wid & 3;         // 0..3  (N quarter)

    // XCD-bijective swizzle: 512 blocks, 64/XCD; each XCD gets 4 contiguous
    // bm2 slabs x all 16 bn2 -> per-kt L2 working set ~640 KB.
    const int bid = blockIdx.x;
    const int swz = (bid & 7) * 64 + (bid >> 3);
    const int bm2 = swz >> 4;         // 0..31
    const int bn2 = swz & 15;         // 0..15

    // global element bases of the four packed panels this block consumes
    const size_t aT0 = (size_t)(bm2 * 2    ) * KT * TILE_ELEMS;
    const size_t aT1 = (size_t)(bm2 * 2 + 1) * KT * TILE_ELEMS;
    const size_t wT0 = (size_t)(bn2 * 2    ) * KT * TILE_ELEMS;
    const size_t wT1 = (size_t)(bn2 * 2 + 1) * KT * TILE_ELEMS;

    f32x4 acc[8][4];
#pragma unroll
    for (int i = 0; i < 8; ++i)
#pragma unroll
        for (int j = 0; j < 4; ++j)
            acc[i][j] = f32x4{0.f, 0.f, 0.f, 0.f};

    const int cswz = l16 & 7;
    const int aSub = wm2 * TILE_ELEMS;              // A sub-tile base (elems)
    const int bSub = (wn2 >> 1) * TILE_ELEMS;       // W sub-tile base
    const int bRowW = (wn2 & 1) * 64 + l16;         // + ni*16 (row in sub)

    // -------- prologue: stage kt=0 into buffer 0 --------
    {
        g2l16(aP + aT0 + tid * 8,        &sA[0][0 * 4096 + tid * 8]);
        g2l16(wP + wT0 + tid * 8,        &sB[0][0 * 4096 + tid * 8]);
        g2l16(aP + aT0 + 4096 + tid * 8, &sA[0][1 * 4096 + tid * 8]);
        g2l16(wP + wT0 + 4096 + tid * 8, &sB[0][1 * 4096 + tid * 8]);
        g2l16(aP + aT1 + tid * 8,        &sA[0][2 * 4096 + tid * 8]);
        g2l16(wP + wT1 + tid * 8,        &sB[0][2 * 4096 + tid * 8]);
        g2l16(aP + aT1 + 4096 + tid * 8, &sA[0][3 * 4096 + tid * 8]);
        g2l16(wP + wT1 + 4096 + tid * 8, &sB[0][3 * 4096 + tid * 8]);
    }
    asm volatile("s_waitcnt vmcnt(0)" ::: "memory");
    __builtin_amdgcn_s_barrier();

    int cur = 0;
    for (int kt = 0; kt < KT; ++kt) {
        const int nb = cur ^ 1;
        const bool pf = (kt + 1) < KT;
        const size_t tOff = (size_t)(kt + 1) * TILE_ELEMS;
        const __bf16* sAc = &sA[cur][0];
        const __bf16* sBc = &sB[cur][0];

        bf16x8 bfr[4][2];                 // B frags held across phases

#pragma unroll
        for (int ph = 0; ph < 4; ++ph) {
            // ---- ds-read register subtile for this phase ----
            bf16x8 af[2][2];
#pragma unroll
            for (int j = 0; j < 2; ++j)
#pragma unroll
                for (int ks = 0; ks < 2; ++ks) {
                    const int cp = (quad + ks * 4) ^ cswz;
                    af[j][ks] = *(const bf16x8*)
                        &sAc[aSub + ((2 * ph + j) * 16 + l16) * 64 + cp * 8];
                }
            if (ph == 0) {
#pragma unroll
                for (int ni = 0; ni < 4; ++ni)
#pragma unroll
                    for (int ks = 0; ks < 2; ++ks) {
                        const int cp = (quad + ks * 4) ^ cswz;
                        bfr[ni][ks] = *(const bf16x8*)
                            &sBc[bSub + (bRowW + ni * 16) * 64 + cp * 8];
                    }
            }

            // ---- issue next-tile prefetch early (phases 0-1 only) ----
            if (pf && ph == 0) {
                g2l16(aP + aT0 + tOff + tid * 8,        &sA[nb][0 * 4096 + tid * 8]);
                g2l16(wP + wT0 + tOff + tid * 8,        &sB[nb][0 * 4096 + tid * 8]);
                g2l16(aP + aT0 + tOff + 4096 + tid * 8, &sA[nb][1 * 4096 + tid * 8]);
                g2l16(wP + wT0 + tOff + 4096 + tid * 8, &sB[nb][1 * 4096 + tid * 8]);
            }
            if (pf && ph == 1) {
                g2l16(aP + aT1 + tOff + tid * 8,        &sA[nb][2 * 4096 + tid * 8]);
                g2l16(wP + wT1 + tOff + tid * 8,        &sB[nb][2 * 4096 + tid * 8]);
                g2l16(aP + aT1 + tOff + 4096 + tid * 8, &sA[nb][3 * 4096 + tid * 8]);
                g2l16(wP + wT1 + tOff + 4096 + tid * 8, &sB[nb][3 * 4096 + tid * 8]);
            }

            __builtin_amdgcn_s_barrier();

            // ---- MFMA cluster (one 32-row quadrant x 64 cols x K=64) ----
            __builtin_amdgcn_s_setprio(1);
#pragma unroll
            for (int j = 0; j < 2; ++j)
#pragma unroll
                for (int ni = 0; ni < 4; ++ni)
#pragma unroll
                    for (int ks = 0; ks < 2; ++ks)
                        acc[2 * ph + j][ni] =
                            __builtin_amdgcn_mfma_f32_16x16x32_bf16(
                                af[j][ks], bfr[ni][ks], acc[2 * ph + j][ni],
                                0, 0, 0);
            __builtin_amdgcn_s_setprio(0);

            if (ph < 3) {
                __builtin_amdgcn_s_barrier();
            } else {
                // buffer swap: next tile's g2l must have landed; this is the
                // ONLY vmcnt drain per K-tile, covered by ~3 phases of MFMA.
                asm volatile("s_waitcnt vmcnt(0)" ::: "memory");
                __builtin_amdgcn_s_barrier();
                __builtin_amdgcn_sched_barrier(0);
            }
        }
        cur = nb;
    }

    // epilogue: C/D layout col = lane&15, row = quad*4 + reg; fp32 out + bias
    const int colBase = bn2 * 256 + wn2 * 64 + l16;
    const int rowBase = bm2 * 256 + wm2 * 128 + quad * 4;
#pragma unroll
    for (int ni = 0; ni < 4; ++ni) {
        const int col = colBase + ni * 16;
        const float bv = bias[col];
#pragma unroll
        for (int mi = 0; mi < 8; ++mi) {
            const int row = rowBase + mi * 16;
#pragma unroll
            for (int r = 0; r < 4; ++r)
                C[(size_t)(row + r) * N_DIM + col] = acc[mi][ni][r] + bv;
        }
    }
}

// ---------------- Fallback (round-3 kernel, ws too small) ----------------
__global__ __launch_bounds__(256, 2) void linear_f32_bf16mfma_kernel(
    const float* __restrict__ A, const float* __restrict__ W,
    const float* __restrict__ bias, float* __restrict__ C)
{
    __shared__ __attribute__((aligned(16))) __bf16 sA[128 * 64];
    __shared__ __attribute__((aligned(16))) __bf16 sB[128 * 64];

    const int tid  = threadIdx.x;
    const int lane = tid & 63;
    const int wave = tid >> 6;
    const int quad = lane >> 4;
    const int l16  = lane & 15;
    const int wm   = wave >> 1;
    const int wn   = wave & 1;
    const int bn = blockIdx.x;
    const int bm = blockIdx.y;
    const int srow = tid >> 3;
    const int scol = (tid & 7) * 8;

    const float* aBase = A + (size_t)(bm * 128 + srow) * K_DIM + scol;
    const float* bBase = W + (size_t)(bn * 128 + srow) * K_DIM + scol;

    f32x4 acc[4][4];
#pragma unroll
    for (int i = 0; i < 4; ++i)
#pragma unroll
        for (int j = 0; j < 4; ++j)
            acc[i][j] = f32x4{0.f, 0.f, 0.f, 0.f};

    const int aRow = wm * 64 + l16;
    const int bRow = wn * 64 + l16;
    const int kOff = quad * 8;

    for (int k0 = 0; k0 < K_DIM; k0 += 64) {
        f32x4 ga[4][2], gb[4][2];
#pragma unroll
        for (int it = 0; it < 4; ++it) {
            const float* pa = aBase + (size_t)(it * 32) * K_DIM + k0;
            const float* pb = bBase + (size_t)(it * 32) * K_DIM + k0;
            ga[it][0] = *(const f32x4*)(pa);
            ga[it][1] = *(const f32x4*)(pa + 4);
            gb[it][0] = *(const f32x4*)(pb);
            gb[it][1] = *(const f32x4*)(pb + 4);
        }
        u32x4 wa[4], wb[4];
#pragma unroll
        for (int it = 0; it < 4; ++it) {
            wa[it] = u32x4{pack2bf(ga[it][0][0], ga[it][0][1]),
                           pack2bf(ga[it][0][2], ga[it][0][3]),
                           pack2bf(ga[it][1][0], ga[it][1][1]),
                           pack2bf(ga[it][1][2], ga[it][1][3])};
            wb[it] = u32x4{pack2bf(gb[it][0][0], gb[it][0][1]),
                           pack2bf(gb[it][0][2], gb[it][0][3]),
                           pack2bf(gb[it][1][0], gb[it][1][1]),
                           pack2bf(gb[it][1][2], gb[it][1][3])};
        }
        __syncthreads();
#pragma unroll
        for (int it = 0; it < 4; ++it) {
            *(u32x4*)&sA[tid * 8 + it * 2048] = wa[it];
            *(u32x4*)&sB[tid * 8 + it * 2048] = wb[it];
        }
        __syncthreads();
#pragma unroll
        for (int ks = 0; ks < 64; ks += 32) {
            bf16x8 af[4], bfr[4];
#pragma unroll
            for (int mi = 0; mi < 4; ++mi)
                af[mi] = *(const bf16x8*)&sA[(aRow + mi * 16) * 64 + ks + kOff];
#pragma unroll
            for (int ni = 0; ni < 4; ++ni)
                bfr[ni] = *(const bf16x8*)&sB[(bRow + ni * 16) * 64 + ks + kOff];
#pragma unroll
            for (int mi = 0; mi < 4; ++mi)
#pragma unroll
                for (int ni = 0; ni < 4; ++ni)
                    acc[mi][ni] = __builtin_amdgcn_mfma_f32_16x16x32_bf16(
                        af[mi], bfr[ni], acc[mi][ni], 0, 0, 0);
        }
    }
    const int colBase = bn * 128 + wn * 64 + l16;
    const int rowBase = bm * 128 + wm * 64 + quad * 4;
#pragma unroll
    for (int ni = 0; ni < 4; ++ni) {
        const int col = colBase + ni * 16;
        const float bv = bias[col];
#pragma unroll
        for (int mi = 0; mi < 4; ++mi) {
            const int row = rowBase + mi * 16;
#pragma unroll
            for (int r = 0; r < 4; ++r)
                C[(size_t)(row + r) * N_DIM + col] = acc[mi][ni][r] + bv;
        }
    }
}

extern "C" void kernel_launch(void* const* d_in, const int* in_sizes, int n_in,
                              void* d_out, int out_size, void* d_ws, size_t ws_size,
                              hipStream_t stream) {
    const float* x = (const float*)d_in[0];   // [8192, 4096]
    const float* w = (const float*)d_in[1];   // [4096, 4096]
    const float* b = (const float*)d_in[2];   // [4096]
    float* out = (float*)d_out;

    if (ws_size >= A_PACK_BYTES + W_PACK_BYTES) {
        u32x4* aP = (u32x4*)d_ws;
        u32x4* wP = (u32x4*)((char*)d_ws + A_PACK_BYTES);
        const int total_chunks = A_CHUNKS + W_CHUNKS_N;
        pack_bf16_kernel<<<total_chunks / 256, 256, 0, stream>>>(x, w, aP, wP);
        gemm256_8ph_kernel<<<dim3(512), 512, 0, stream>>>(
            (const u16*)aP, (const u16*)wP, b, out);
    } else {
        dim3 grid(N_DIM / 128, M_DIM / 128);
        linear_f32_bf16mfma_kernel<<<grid, 256, 0, stream>>>(x, w, b, out);
    }
}

// Round 5
// 486.423 us; speedup vs baseline: 1.9374x; 1.0030x over previous
//
#include <hip/hip_runtime.h>
#include <hip/hip_bf16.h>

// Linear: C[M,N] = A[M,K] @ W[N,K]^T + bias[N]. fp32 in/out (harness maps fp16
// reference -> fp32 buffers), bf16 MFMA compute (2% threshold).
//
// Round 12: r4's "4-phase" schedule still degenerated to a per-K-tile
// vmcnt(0) drain (all 4 half-tiles needed at next tile's phase 0 -> the
// counted wait had nothing to skip). m218: 8-phase-with-drain0 == 1-phase;
// counted vmcnt IS the gain. This round makes the pipeline genuinely deep:
//   * packed layout re-cut into 128x32-k blocks (8 KB), 2-bit XOR swizzle
//     cp = c ^ ((row>>1)&3)  (2 lanes/16B-slot at rows 8 apart = 2-way LDS
//     conflict = free; global_load_lds stays linear - pack pre-swizzles).
//   * GEMM: ring of 4 LDS slots x 32 KB, slot j = K-step j (32 k): A-pair +
//     B-pair. During step j issue stage(j+3) -> 3 K-steps (~4500 cyc) cover;
//     per-step wait = vmcnt(8) (keep 2 newest stages in flight), vmcnt(4)/(0)
//     only in the last two steps. ONE raw s_barrier per K-step (128 total vs
//     r4's 512); asm "memory" fences instead of __syncthreads (which would
//     re-insert the vmcnt(0) drain).
//   * MFMA core / fragment convention / epilogue byte-identical to r4
//     (K=32 step = single k-slice, lane k = quad*8).
// Predicted: gemm 185-215 us, MfmaUtil 55-65%; total ~430-460.

typedef unsigned short u16;
typedef unsigned int u32;
typedef __bf16 bf16x8 __attribute__((ext_vector_type(8)));
typedef float f32x4 __attribute__((ext_vector_type(4)));
typedef u32 u32x4 __attribute__((ext_vector_type(4)));

#define M_DIM 8192
#define N_DIM 4096
#define K_DIM 4096

#define NT 128                          // 32-k K-steps
#define BLK_ELEMS 4096                  // 128 rows x 32 k per packed block
#define SLOT_ELEMS 16384                // ring slot: A0,A1,B0,B1 blocks

#define A_CHUNKS ((M_DIM / 128) * NT * 128 * 4)   // 4,194,304 16B chunks
#define W_CHUNKS ((N_DIM / 128) * NT * 128 * 4)   // 2,097,152
#define A_PACK_BYTES ((size_t)A_CHUNKS * 16)      // 64 MiB
#define W_PACK_BYTES ((size_t)W_CHUNKS * 16)      // 32 MiB

// pack two fp32 -> (bf16(hi)<<16)|bf16(lo) by byte-perm truncation
__device__ __forceinline__ u32 pack2bf(float lo, float hi) {
    return __builtin_amdgcn_perm(__float_as_uint(hi), __float_as_uint(lo),
                                 0x07060302u);
}

__device__ __forceinline__ void g2l16(const u16* g, __bf16* l) {
    __builtin_amdgcn_global_load_lds((__attribute__((address_space(1))) void*)g,
                                     (__attribute__((address_space(3))) void*)l,
                                     16, 0, 0);
}

// ---------------- Phase 1: convert + block-pack + swizzle ----------------
// Packed layout: [panel][kstep][row][cp], 16B chunk cp at row r holds source
// chunk c = cp ^ ((r>>1)&3). One thread per chunk. A wave covers 16 rows x 4
// chunks: per row the 4 chunks are a permutation of one contiguous 128 B
// source segment (coalesced); writes fully linear (1 KiB/wave).
__global__ __launch_bounds__(256) void pack_bf16_kernel(
    const float* __restrict__ A, const float* __restrict__ W,
    u32x4* __restrict__ aP, u32x4* __restrict__ wP)
{
    int gid = blockIdx.x * 256 + threadIdx.x;
    const float* src;
    u32x4* dst;
    int id;
    if (gid < A_CHUNKS) { src = A; dst = aP; id = gid; }
    else                { src = W; dst = wP; id = gid - A_CHUNKS; }

    const int cp  = id & 3;
    const int row = (id >> 2) & 127;
    const int j   = (id >> 9) & 127;          // k-step
    const int mp  = id >> 16;                 // 128-row panel
    const int c   = cp ^ ((row >> 1) & 3);    // source chunk

    const float* p = src + (size_t)(mp * 128 + row) * K_DIM + j * 32 + c * 8;
    f32x4 v0 = __builtin_nontemporal_load((const f32x4*)(p));
    f32x4 v1 = __builtin_nontemporal_load((const f32x4*)(p + 4));
    dst[id] = u32x4{pack2bf(v0[0], v0[1]), pack2bf(v0[2], v0[3]),
                    pack2bf(v1[0], v1[1]), pack2bf(v1[2], v1[3])};
}

// ---------------- Phase 2: 256x256 ring-4 counted-vmcnt GEMM ---------------
// 512 thr / 8 waves (2M x 4N); per-wave output 128x64. Ring slot j&3 holds
// K-step j (A panels 2bm2,2bm2+1 + W panels 2bn2,2bn2+1, 8 KB each).
// Steady state: stage(j+3) issued during step j; wait vmcnt(8) keeps the two
// newest stages in flight. 4 g2l per thread per stage (16 B each).
__global__ __launch_bounds__(512, 2) void gemm_ring4_kernel(
    const u16* __restrict__ aP,      // packed A blocks (128x32, swizzled)
    const u16* __restrict__ wP,      // packed W blocks (128x32, swizzled)
    const float* __restrict__ bias,  // [N] fp32
    float* __restrict__ C)           // [M, N] fp32
{
    __shared__ __attribute__((aligned(16))) __bf16 ring[4][SLOT_ELEMS];

    const int tid  = threadIdx.x;
    const int lane = tid & 63;
    const int wid  = tid >> 6;        // 0..7
    const int quad = lane >> 4;
    const int l16  = lane & 15;
    const int wm2  = wid >> 2;        // 0..1  (M half)
    const int wn2  = wid & 3;         // 0..3  (N quarter)

    // XCD-bijective swizzle: 512 blocks, 64/XCD contiguous tile range.
    const int bid = blockIdx.x;
    const int swz = (bid & 7) * 64 + (bid >> 3);
    const int bm2 = swz >> 4;         // 0..31
    const int bn2 = swz & 15;         // 0..15

    const u16* a0 = aP + (size_t)(bm2 * 2    ) * NT * BLK_ELEMS + tid * 8;
    const u16* a1 = aP + (size_t)(bm2 * 2 + 1) * NT * BLK_ELEMS + tid * 8;
    const u16* w0 = wP + (size_t)(bn2 * 2    ) * NT * BLK_ELEMS + tid * 8;
    const u16* w1 = wP + (size_t)(bn2 * 2 + 1) * NT * BLK_ELEMS + tid * 8;

    auto stage = [&](int t) {
        __bf16* s = &ring[t & 3][tid * 8];
        const size_t o = (size_t)t * BLK_ELEMS;
        g2l16(a0 + o, s);
        g2l16(a1 + o, s + BLK_ELEMS);
        g2l16(w0 + o, s + 2 * BLK_ELEMS);
        g2l16(w1 + o, s + 3 * BLK_ELEMS);
    };

    f32x4 acc[8][4];
#pragma unroll
    for (int i = 0; i < 8; ++i)
#pragma unroll
        for (int j = 0; j < 4; ++j)
            acc[i][j] = f32x4{0.f, 0.f, 0.f, 0.f};

    // read offsets (elems within slot); swizzle (row>>1)&3 == (l16>>1)&3
    // for all rows we touch (row = multiple-of-16 + l16).
    const int cpq  = ((quad ^ ((l16 >> 1) & 3))) * 8;
    const int aOff = wm2 * BLK_ELEMS + l16 * 32 + cpq;
    const int bOff = 2 * BLK_ELEMS + (wn2 >> 1) * BLK_ELEMS
                   + ((wn2 & 1) * 64 + l16) * 32 + cpq;

    stage(0); stage(1); stage(2);

    for (int j = 0; j < NT; ++j) {
        // counted wait: keep the 2 newest stages (8 ops) in flight.
        if (j + 2 < NT)      asm volatile("s_waitcnt vmcnt(8)" ::: "memory");
        else if (j + 1 < NT) asm volatile("s_waitcnt vmcnt(4)" ::: "memory");
        else                 asm volatile("s_waitcnt vmcnt(0)" ::: "memory");
        __builtin_amdgcn_s_barrier();
        asm volatile("" ::: "memory");   // keep g2l/ds_read after barrier

        if (j + 3 < NT) stage(j + 3);    // slot (j+3)&3 = (j-1)&3, just freed

        const __bf16* L = &ring[j & 3][0];
        bf16x8 af[8], bfr[4];
#pragma unroll
        for (int rb = 0; rb < 8; ++rb)
            af[rb] = *(const bf16x8*)&L[aOff + rb * 512];
#pragma unroll
        for (int nb = 0; nb < 4; ++nb)
            bfr[nb] = *(const bf16x8*)&L[bOff + nb * 512];

        __builtin_amdgcn_s_setprio(1);
#pragma unroll
        for (int rb = 0; rb < 8; ++rb)
#pragma unroll
            for (int nb = 0; nb < 4; ++nb)
                acc[rb][nb] = __builtin_amdgcn_mfma_f32_16x16x32_bf16(
                    af[rb], bfr[nb], acc[rb][nb], 0, 0, 0);
        __builtin_amdgcn_s_setprio(0);
    }

    // epilogue: C/D layout col = lane&15, row = quad*4 + reg; fp32 out + bias
    const int colBase = bn2 * 256 + wn2 * 64 + l16;
    const int rowBase = bm2 * 256 + wm2 * 128 + quad * 4;
#pragma unroll
    for (int nb = 0; nb < 4; ++nb) {
        const int col = colBase + nb * 16;
        const float bv = bias[col];
#pragma unroll
        for (int rb = 0; rb < 8; ++rb) {
            const int row = rowBase + rb * 16;
#pragma unroll
            for (int r = 0; r < 4; ++r)
                C[(size_t)(row + r) * N_DIM + col] = acc[rb][nb][r] + bv;
        }
    }
}

// ---------------- Fallback (round-3 kernel, ws too small) ----------------
__global__ __launch_bounds__(256, 2) void linear_f32_bf16mfma_kernel(
    const float* __restrict__ A, const float* __restrict__ W,
    const float* __restrict__ bias, float* __restrict__ C)
{
    __shared__ __attribute__((aligned(16))) __bf16 sA[128 * 64];
    __shared__ __attribute__((aligned(16))) __bf16 sB[128 * 64];

    const int tid  = threadIdx.x;
    const int lane = tid & 63;
    const int wave = tid >> 6;
    const int quad = lane >> 4;
    const int l16  = lane & 15;
    const int wm   = wave >> 1;
    const int wn   = wave & 1;
    const int bn = blockIdx.x;
    const int bm = blockIdx.y;
    const int srow = tid >> 3;
    const int scol = (tid & 7) * 8;

    const float* aBase = A + (size_t)(bm * 128 + srow) * K_DIM + scol;
    const float* bBase = W + (size_t)(bn * 128 + srow) * K_DIM + scol;

    f32x4 acc[4][4];
#pragma unroll
    for (int i = 0; i < 4; ++i)
#pragma unroll
        for (int j = 0; j < 4; ++j)
            acc[i][j] = f32x4{0.f, 0.f, 0.f, 0.f};

    const int aRow = wm * 64 + l16;
    const int bRow = wn * 64 + l16;
    const int kOff = quad * 8;

    for (int k0 = 0; k0 < K_DIM; k0 += 64) {
        f32x4 ga[4][2], gb[4][2];
#pragma unroll
        for (int it = 0; it < 4; ++it) {
            const float* pa = aBase + (size_t)(it * 32) * K_DIM + k0;
            const float* pb = bBase + (size_t)(it * 32) * K_DIM + k0;
            ga[it][0] = *(const f32x4*)(pa);
            ga[it][1] = *(const f32x4*)(pa + 4);
            gb[it][0] = *(const f32x4*)(pb);
            gb[it][1] = *(const f32x4*)(pb + 4);
        }
        u32x4 wa[4], wb[4];
#pragma unroll
        for (int it = 0; it < 4; ++it) {
            wa[it] = u32x4{pack2bf(ga[it][0][0], ga[it][0][1]),
                           pack2bf(ga[it][0][2], ga[it][0][3]),
                           pack2bf(ga[it][1][0], ga[it][1][1]),
                           pack2bf(ga[it][1][2], ga[it][1][3])};
            wb[it] = u32x4{pack2bf(gb[it][0][0], gb[it][0][1]),
                           pack2bf(gb[it][0][2], gb[it][0][3]),
                           pack2bf(gb[it][1][0], gb[it][1][1]),
                           pack2bf(gb[it][1][2], gb[it][1][3])};
        }
        __syncthreads();
#pragma unroll
        for (int it = 0; it < 4; ++it) {
            *(u32x4*)&sA[tid * 8 + it * 2048] = wa[it];
            *(u32x4*)&sB[tid * 8 + it * 2048] = wb[it];
        }
        __syncthreads();
#pragma unroll
        for (int ks = 0; ks < 64; ks += 32) {
            bf16x8 af[4], bfr[4];
#pragma unroll
            for (int mi = 0; mi < 4; ++mi)
                af[mi] = *(const bf16x8*)&sA[(aRow + mi * 16) * 64 + ks + kOff];
#pragma unroll
            for (int ni = 0; ni < 4; ++ni)
                bfr[ni] = *(const bf16x8*)&sB[(bRow + ni * 16) * 64 + ks + kOff];
#pragma unroll
            for (int mi = 0; mi < 4; ++mi)
#pragma unroll
                for (int ni = 0; ni < 4; ++ni)
                    acc[mi][ni] = __builtin_amdgcn_mfma_f32_16x16x32_bf16(
                        af[mi], bfr[ni], acc[mi][ni], 0, 0, 0);
        }
    }
    const int colBase = bn * 128 + wn * 64 + l16;
    const int rowBase = bm * 128 + wm * 64 + quad * 4;
#pragma unroll
    for (int ni = 0; ni < 4; ++ni) {
        const int col = colBase + ni * 16;
        const float bv = bias[col];
#pragma unroll
        for (int mi = 0; mi < 4; ++mi) {
            const int row = rowBase + mi * 16;
#pragma unroll
            for (int r = 0; r < 4; ++r)
                C[(size_t)(row + r) * N_DIM + col] = acc[mi][ni][r] + bv;
        }
    }
}

extern "C" void kernel_launch(void* const* d_in, const int* in_sizes, int n_in,
                              void* d_out, int out_size, void* d_ws, size_t ws_size,
                              hipStream_t stream) {
    const float* x = (const float*)d_in[0];   // [8192, 4096]
    const float* w = (const float*)d_in[1];   // [4096, 4096]
    const float* b = (const float*)d_in[2];   // [4096]
    float* out = (float*)d_out;

    if (ws_size >= A_PACK_BYTES + W_PACK_BYTES) {
        u32x4* aP = (u32x4*)d_ws;
        u32x4* wP = (u32x4*)((char*)d_ws + A_PACK_BYTES);
        const int total_chunks = A_CHUNKS + W_CHUNKS;
        pack_bf16_kernel<<<total_chunks / 256, 256, 0, stream>>>(x, w, aP, wP);
        gemm_ring4_kernel<<<dim3(512), 512, 0, stream>>>(
            (const u16*)aP, (const u16*)wP, b, out);
    } else {
        dim3 grid(N_DIM / 128, M_DIM / 128);
        linear_f32_bf16mfma_kernel<<<grid, 256, 0, stream>>>(x, w, b, out);
    }
}